// Round 11
// baseline (397.493 us; speedup 1.0000x reference)
//
#include <hip/hip_runtime.h>
#include <hip/hip_bf16.h>
#include <math.h>

#define NN 20000
#define NE 320000
#define C0I 32
#define C1I 16
#define C0O 64
#define C1O 16
#define EPSF 1e-8f
#define STAGE_TOTAL 1671264   // total staged f32 elements
#define STAGE_V4    417816    // /4
#define RSTR 84               // LDS row stride (84 mod 32 = 20 -> 2-way max, free)

using bf16 = __hip_bfloat16;

__device__ __forceinline__ float bb2f(unsigned short u) {
    return __uint_as_float(((unsigned)u) << 16);
}

// wave-level LDS fence: drain outstanding ds ops + forbid compile-time motion
__device__ __forceinline__ void lds_fence() {
    asm volatile("s_waitcnt lgkmcnt(0)" ::: "memory");
    __builtin_amdgcn_sched_barrier(0);
}

// ---- kA: detect dtype + stage all float inputs as f32 (vectorized) + zero cnt ----
__global__ __launch_bounds__(256) void se3_convert(
    const void* s0, const void* s1, const void* s2, const void* s3,
    const void* s4, const void* s5, const void* s6, const void* s7,
    const void* s8, const void* s9, const void* s10, const void* s11,
    int* __restrict__ flag, float* __restrict__ dst, int* __restrict__ cnt) {
    __shared__ int sj;
    if (threadIdx.x == 0) sj = 0;
    __syncthreads();
    {   // f32 data read as bf16 at even indices shows junk exponents
        const unsigned short* p = (const unsigned short*)s0;
        bool junk = false;
        int i0 = threadIdx.x * 8;
#pragma unroll
        for (int k = 0; k < 4; ++k) {
            float v = bb2f(p[i0 + k * 2]);
            if (!(fabsf(v) < 1e3f)) junk = true;
        }
        if (junk) atomicOr(&sj, 1);
    }
    __syncthreads();
    int isf32 = sj;
    int gid = blockIdx.x * 256 + threadIdx.x;
    if (gid == 0) *flag = isf32;
    if (gid < NN) cnt[gid] = 0;
    if (gid >= STAGE_V4) return;

    const void* src; int off;  // vec4 units
    if      (gid < 160000) { src = s0;  off = gid; }
    else if (gid < 400000) { src = s1;  off = gid - 160000; }
    else if (gid < 415000) { src = s2;  off = gid - 400000; }
    else if (gid < 415512) { src = s3;  off = gid - 415000; }
    else if (gid < 416024) { src = s4;  off = gid - 415512; }
    else if (gid < 416280) { src = s5;  off = gid - 416024; }
    else if (gid < 416792) { src = s6;  off = gid - 416280; }
    else if (gid < 417048) { src = s7;  off = gid - 416792; }
    else if (gid < 417176) { src = s8;  off = gid - 417048; }
    else if (gid < 417240) { src = s9;  off = gid - 417176; }
    else if (gid < 417752) { src = s10; off = gid - 417240; }
    else                   { src = s11; off = gid - 417752; }

    float4 v;
    if (isf32) {
        v = ((const float4*)src)[off];
    } else {
        ushort4 u = ((const ushort4*)src)[off];
        v = make_float4(bb2f(u.x), bb2f(u.y), bb2f(u.z), bb2f(u.w));
    }
    ((float4*)dst)[gid] = v;
}

// ---- kB: histogram + wqkc[32][48] + concatenated epilogue matrices ----
__global__ __launch_bounds__(256) void se3_hist(
    const int* __restrict__ ei, int* __restrict__ cnt,
    const float* __restrict__ wq0, const float* __restrict__ wk00,
    const float* __restrict__ wk10,
    const float* __restrict__ wv00, const float* __restrict__ wv10,
    const float* __restrict__ wv01, const float* __restrict__ wv11,
    const float* __restrict__ ws0, const float* __restrict__ ws1,
    float* __restrict__ wqkc, float* __restrict__ M0cat, float* __restrict__ M1cat) {
    int gid = blockIdx.x * 256 + threadIdx.x;
    if (gid < 1536) {
        int cp = gid / 48, c = gid % 48;
        float a = 0.f;
        if (c < 32) { for (int j = 0; j < C0O; ++j) a += wq0[cp*C0O+j] * wk00[c*C0O+j]; }
        else        { for (int j = 0; j < C0O; ++j) a += wq0[cp*C0O+j] * wk10[(c-32)*C0O+j]; }
        wqkc[gid] = a;
    } else if (gid < 1536 + 5120) {
        int i = gid - 1536;
        int r = i >> 6, j = i & 63;
        M0cat[i] = (r < 32) ? wv00[r*64+j] : (r < 48) ? wv10[(r-32)*64+j] : ws0[(r-48)*64+j];
    } else if (gid < 1536 + 5120 + 1024) {
        int i = gid - 6656;
        int r = i >> 4, f = i & 15;
        M1cat[i] = (r < 16) ? wv11[r*16+f] : (r < 48) ? wv01[(r-16)*16+f] : ws1[(r-48)*16+f];
    }
    if (gid < NE) atomicAdd(&cnt[ei[NE + gid]], 1);
}

// ---- kC: exclusive scan of cnt[NN] -> rowptr, wptr; reset work-steal counter ----
__global__ __launch_bounds__(1024) void se3_scan(
    const int* __restrict__ cnt, int* __restrict__ rowptr, int* __restrict__ wptr,
    int* __restrict__ nodectr) {
    __shared__ int tmp[1024];
    int t = threadIdx.x;
    if (t == 0) *nodectr = 0;
    int base = t * 20;
    int v[20]; int s = 0;
#pragma unroll
    for (int i = 0; i < 20; ++i) {
        int idx = base + i;
        int c = (idx < NN) ? cnt[idx] : 0;
        v[i] = s; s += c;
    }
    tmp[t] = s;
    __syncthreads();
    for (int off = 1; off < 1024; off <<= 1) {
        int x = (t >= off) ? tmp[t - off] : 0;
        __syncthreads();
        tmp[t] += x;
        __syncthreads();
    }
    int tb = (t > 0) ? tmp[t - 1] : 0;
#pragma unroll
    for (int i = 0; i < 20; ++i) {
        int idx = base + i;
        if (idx < NN) { int r = tb + v[i]; rowptr[idx] = r; wptr[idx] = r; }
    }
    if (t == 1023) rowptr[NN] = NE;
}

// ---- kD: scatter src node ids into dst-sorted CSR order ----
__global__ __launch_bounds__(256) void se3_scatter(
    const int* __restrict__ ei, int* __restrict__ wptr, int* __restrict__ csr_src) {
    int e = blockIdx.x * 256 + threadIdx.x;
    if (e >= NE) return;
    int d = ei[NE + e];
    int off = atomicAdd(&wptr[d], 1);
    csr_src[off] = ei[e];
}

// ---- kF: persistent-wave work-stealing attention. 1024 blocks x 4 waves;
//      each wave pops node indices from a global atomic counter (fixes the
//      1-WG-per-~16cy dispatch limit of a 20000-block grid AND intra-block
//      straggling of multi-wave blocks). Per-node body = round-10 proven code;
//      Phase-B w/Y broadcast now via W4[16][4] LDS (1 b128 broadcast read per
//      edge instead of 4 ds_bpermute), fence-protected. ----
__global__ __launch_bounds__(256) void se3_fused(
    const float* __restrict__ x0, const float* __restrict__ x1,
    const float* __restrict__ pos, const float* __restrict__ wqkc,
    const int* __restrict__ rowptr, const int* __restrict__ csr_src,
    const float* __restrict__ M0cat, const float* __restrict__ M1cat,
    const int* __restrict__ flag, int* __restrict__ nodectr,
    void* __restrict__ out) {
    __shared__ __align__(16) float rows[4][16][RSTR];
    __shared__ float sq[4][48];
    __shared__ __align__(16) float sW4[4][16][4];

    int tid = threadIdx.x;
    int wv = tid >> 6, lane = tid & 63;
    float (*R)[RSTR] = rows[wv];
    float* q = sq[wv];
    float (*W4)[4] = sW4[wv];
    int isf32 = *flag;
    int e4 = lane >> 2, j4 = lane & 3;
    int cc = (lane >= 32 && lane < 48) ? (lane - 32) : 0;

    for (;;) {
        int n;
        if (lane == 0) n = atomicAdd(nodectr, 1);
        n = __shfl(n, 0);
        if (n >= NN) break;

        // ---- inline qvec: q[c] = sum_cp x0n[cp] * wqkc[cp][c] ----
        float x0v_n = (lane < 32) ? x0[(size_t)n * 32 + lane] : 0.f;
        {
            int li = (lane < 48) ? lane : 0;
            float qh = 0.f;
            for (int cp = 0; cp < 32; ++cp)
                qh += __shfl(x0v_n, cp) * wqkc[cp * 48 + li];
            if (lane < 48) q[lane] = qh;
        }
        float pnx = pos[n*3], pny = pos[n*3+1], pnz = pos[n*3+2];
        int p0 = rowptr[n], deg = rowptr[n+1] - p0;

        float m = -INFINITY, zz = 0.f;
        float aggA = 0.f, aggB = 0.f, Cx = 0.f, Cy = 0.f, Cz = 0.f;

        for (int base = 0; base < deg; base += 16) {
            int nch = min(16, deg - base);
            float Yx = 0.f, Yy = 0.f, Yz = 0.f;
            // ---- stage: 4 lanes per edge; Y computed by all 4 lanes into regs ----
            if (e4 < nch) {
                int s_e = csr_src[p0 + base + e4];
                float rx = pnx - pos[s_e*3], ry = pny - pos[s_e*3+1], rz = pnz - pos[s_e*3+2];
                float inv = 1.f / (sqrtf(rx*rx + ry*ry + rz*rz) + EPSF);
                Yx = rx*inv; Yy = ry*inv; Yz = rz*inv;
                const float4* px0 = (const float4*)(x0 + (size_t)s_e * 32);
                float4 a0 = px0[j4*2], a1 = px0[j4*2+1];
                *(float4*)&R[e4][j4*8]     = a0;
                *(float4*)&R[e4][j4*8+4]   = a1;
                const float4* px1 = (const float4*)(x1 + (size_t)s_e * 48);
                float4 b0 = px1[j4*3], b1 = px1[j4*3+1], b2 = px1[j4*3+2];
                *(float4*)&R[e4][32+j4*12]   = b0;
                *(float4*)&R[e4][32+j4*12+4] = b1;
                *(float4*)&R[e4][32+j4*12+8] = b2;
            }
            lds_fence();   // stage + q writes visible before cross-lane reads
            // ---- logits: lane (e4,j4) covers features c = j4+4k ----
            float part = 0.f;
            if (e4 < nch) {
#pragma unroll
                for (int k = 0; k < 12; ++k) {
                    int c = j4 + 4*k;
                    float kv;
                    if (c < 32) kv = R[e4][c];
                    else {
                        int c1 = c - 32;
                        kv = R[e4][32+3*c1]*Yx + R[e4][32+3*c1+1]*Yy + R[e4][32+3*c1+2]*Yz;
                    }
                    part += kv * q[c];
                }
            }
            part += __shfl_xor(part, 1);
            part += __shfl_xor(part, 2);
            float lg = (e4 < nch) ? part * 0.125f : -INFINITY;   // 1/sqrt(64)
            float mc = lg;
            mc = fmaxf(mc, __shfl_xor(mc, 4));
            mc = fmaxf(mc, __shfl_xor(mc, 8));
            mc = fmaxf(mc, __shfl_xor(mc, 16));
            mc = fmaxf(mc, __shfl_xor(mc, 32));
            float nm = fmaxf(m, mc);
            float f0 = __expf(m - nm);               // first chunk: exp(-inf)=0
            float w  = (e4 < nch) ? __expf(lg - nm) : 0.f;
            float sw = (j4 == 0) ? w : 0.f;
            sw += __shfl_xor(sw, 1);  sw += __shfl_xor(sw, 2);
            sw += __shfl_xor(sw, 4);  sw += __shfl_xor(sw, 8);
            sw += __shfl_xor(sw, 16); sw += __shfl_xor(sw, 32);
            zz = zz * f0 + sw;
            m = nm;
            aggA *= f0; aggB *= f0; Cx *= f0; Cy *= f0; Cz *= f0;
            // publish per-edge [w,Y] once; Phase B reads it as a broadcast float4
            if (e4 < nch && j4 == 0)
                *(float4*)&W4[e4][0] = make_float4(w, Yx, Yy, Yz);
            lds_fence();   // W4 writes visible before Phase-B reads
            // ---- Phase B: lane = feature; w/Y from W4 broadcast ----
#pragma unroll 4
            for (int e = 0; e < nch; ++e) {
                float4 wy = *(const float4*)&W4[e][0];
                float we = wy.x, Y0 = wy.y, Y1 = wy.z, Y2 = wy.w;
                float x1v = (lane < 48) ? R[e][32 + lane] : 0.f;
                if (lane < 32) {
                    float wx = we * R[e][lane];
                    aggA += wx;
                    Cx += wx * Y0; Cy += wx * Y1; Cz += wx * Y2;
                } else if (lane < 48) {
                    float xd = R[e][32+3*cc]*Y0 + R[e][32+3*cc+1]*Y1 + R[e][32+3*cc+2]*Y2;
                    aggA += we * xd;
                }
                aggB += we * x1v;
            }
            lds_fence();   // Phase-B reads done before next chunk overwrites R
        }

        // ---- epilogue: scratch aliased onto rows (dead after edge loop) ----
        float invz = 1.f / (zz + EPSF);
        float* scw = (float*)rows[wv];
        // feat rows: [0-47] = [a0agg | dotagg], [48-79] = x0n
        // G rows (3r+d layout at 96+): [96-143] x1agg, [144-239] C, [240-287] x1n
        if (lane < 48) {
            scw[lane]       = aggA * invz;
            scw[96 + lane]  = aggB * invz;                 // x1agg, layout 3c+d
            scw[240 + lane] = x1[(size_t)n * 48 + lane];   // x1n
        }
        if (lane < 32) {
            scw[48 + lane] = x0v_n;                        // x0n (from register)
            scw[144 + lane * 3 + 0] = Cx * invz;
            scw[144 + lane * 3 + 1] = Cy * invz;
            scw[144 + lane * 3 + 2] = Cz * invz;
        }
        lds_fence();   // scratch writes visible before cross-lane reads
        float o0 = 0.f;
        for (int r = 0; r < 80; ++r) o0 += scw[r] * M0cat[r * 64 + lane];
        int f = lane / 3, d = lane - 3 * f;
        float o1 = 0.f;
        if (lane < 48) {
            for (int r = 0; r < 64; ++r) o1 += scw[96 + 3 * r + d] * M1cat[r * 16 + f];
        }

        if (isf32) {
            ((float*)out)[(size_t)n * 64 + lane] = o0;
            if (lane < 48) ((float*)out)[(size_t)NN * 64 + (size_t)n * 48 + lane] = o1;
        } else {
            ((bf16*)out)[(size_t)n * 64 + lane] = __float2bfloat16(o0);
            if (lane < 48) ((bf16*)out)[(size_t)NN * 64 + (size_t)n * 48 + lane] = __float2bfloat16(o1);
        }
        lds_fence();   // epilogue scratch reads done before next node's writes
    }
}

extern "C" void kernel_launch(void* const* d_in, const int* in_sizes, int n_in,
                              void* d_out, int out_size, void* d_ws, size_t ws_size,
                              hipStream_t stream) {
    const int* ei = (const int*)d_in[3];

    int* flag  = (int*)d_ws;          // [0]=flag, [1]=nodectr
    int* nodectr = (int*)d_ws + 1;
    float* ws  = (float*)d_ws + 16;
    float* x0f  = ws;                 // 640000
    float* x1f  = x0f + 640000;       // 960000
    float* posf = x1f + 960000;       // 60000
    float* wq0    = posf + 60000;     // 2048
    float* wk00   = wq0 + 2048;       // 2048
    float* wk10   = wk00 + 2048;      // 1024
    float* wv00   = wk10 + 1024;      // 2048
    float* wv10   = wv00 + 2048;      // 1024
    float* wv01   = wv10 + 1024;      // 512
    float* wv11   = wv01 + 512;       // 256
    float* wself0 = wv11 + 256;       // 2048
    float* wself1 = wself0 + 2048;    // 256
    float* wqkc  = ws + STAGE_TOTAL;          // 1536
    float* M0cat = wqkc + 1536;               // 5120
    float* M1cat = M0cat + 5120;              // 1024
    int* cnt     = (int*)(M1cat + 1024);      // NN
    int* rowptr  = cnt + NN;                  // NN+1
    int* wptr    = rowptr + NN + 1;           // NN
    int* csr_src = wptr + NN;                 // NE   (total ~8.3 MB, proven)

    se3_convert<<<1633, 256, 0, stream>>>(d_in[0], d_in[1], d_in[2],
        d_in[4], d_in[5], d_in[6], d_in[7], d_in[8], d_in[9], d_in[10], d_in[11], d_in[12],
        flag, ws, cnt);
    se3_hist<<<1250, 256, 0, stream>>>(ei, cnt, wq0, wk00, wk10,
        wv00, wv10, wv01, wv11, wself0, wself1, wqkc, M0cat, M1cat);
    se3_scan<<<1, 1024, 0, stream>>>(cnt, rowptr, wptr, nodectr);
    se3_scatter<<<1250, 256, 0, stream>>>(ei, wptr, csr_src);
    se3_fused<<<1024, 256, 0, stream>>>(x0f, x1f, posf, wqkc, rowptr, csr_src,
        M0cat, M1cat, flag, nodectr, d_out);
}

// Round 12
// 258.156 us; speedup vs baseline: 1.5397x; 1.5397x over previous
//
#include <hip/hip_runtime.h>
#include <hip/hip_bf16.h>
#include <math.h>

#define NN 20000
#define NE 320000
#define C0I 32
#define C1I 16
#define C0O 64
#define C1O 16
#define EPSF 1e-8f
#define STAGE_TOTAL 1671264   // total staged f32 elements
#define STAGE_V4    417816    // /4
#define RSTR 84               // LDS row stride (84 mod 32 = 20 -> 2-way max, free)

using bf16 = __hip_bfloat16;

__device__ __forceinline__ float bb2f(unsigned short u) {
    return __uint_as_float(((unsigned)u) << 16);
}

// wave-level LDS fence: drain outstanding ds ops + forbid compile-time motion
__device__ __forceinline__ void lds_fence() {
    asm volatile("s_waitcnt lgkmcnt(0)" ::: "memory");
    __builtin_amdgcn_sched_barrier(0);
}

// ---- kA: detect dtype + stage all float inputs as f32 + dst histogram ----
//      (cnt zeroed by hipMemsetAsync before this kernel)
__global__ __launch_bounds__(256) void se3_convert(
    const void* s0, const void* s1, const void* s2, const void* s3,
    const void* s4, const void* s5, const void* s6, const void* s7,
    const void* s8, const void* s9, const void* s10, const void* s11,
    const int* __restrict__ ei,
    int* __restrict__ flag, float* __restrict__ dst, int* __restrict__ cnt) {
    __shared__ int sj;
    if (threadIdx.x == 0) sj = 0;
    __syncthreads();
    {   // f32 data read as bf16 at even indices shows junk exponents
        const unsigned short* p = (const unsigned short*)s0;
        bool junk = false;
        int i0 = threadIdx.x * 8;
#pragma unroll
        for (int k = 0; k < 4; ++k) {
            float v = bb2f(p[i0 + k * 2]);
            if (!(fabsf(v) < 1e3f)) junk = true;
        }
        if (junk) atomicOr(&sj, 1);
    }
    __syncthreads();
    int isf32 = sj;
    int gid = blockIdx.x * 256 + threadIdx.x;
    if (gid == 0) *flag = isf32;
    if (gid < NE) atomicAdd(&cnt[ei[NE + gid]], 1);   // histogram (cnt pre-zeroed)
    if (gid >= STAGE_V4) return;

    const void* src; int off;  // vec4 units
    if      (gid < 160000) { src = s0;  off = gid; }
    else if (gid < 400000) { src = s1;  off = gid - 160000; }
    else if (gid < 415000) { src = s2;  off = gid - 400000; }
    else if (gid < 415512) { src = s3;  off = gid - 415000; }
    else if (gid < 416024) { src = s4;  off = gid - 415512; }
    else if (gid < 416280) { src = s5;  off = gid - 416024; }
    else if (gid < 416792) { src = s6;  off = gid - 416280; }
    else if (gid < 417048) { src = s7;  off = gid - 416792; }
    else if (gid < 417176) { src = s8;  off = gid - 417048; }
    else if (gid < 417240) { src = s9;  off = gid - 417176; }
    else if (gid < 417752) { src = s10; off = gid - 417240; }
    else                   { src = s11; off = gid - 417752; }

    float4 v;
    if (isf32) {
        v = ((const float4*)src)[off];
    } else {
        ushort4 u = ((const ushort4*)src)[off];
        v = make_float4(bb2f(u.x), bb2f(u.y), bb2f(u.z), bb2f(u.w));
    }
    ((float4*)dst)[gid] = v;
}

// ---- kB: block 0: exclusive scan cnt -> rowptr,wptr; blocks 1-8: weight combines ----
__global__ __launch_bounds__(1024) void se3_scanw(
    const int* __restrict__ cnt, int* __restrict__ rowptr, int* __restrict__ wptr,
    const float* __restrict__ wq0, const float* __restrict__ wk00,
    const float* __restrict__ wk10,
    const float* __restrict__ wv00, const float* __restrict__ wv10,
    const float* __restrict__ wv01, const float* __restrict__ wv11,
    const float* __restrict__ ws0, const float* __restrict__ ws1,
    float* __restrict__ wqkc, float* __restrict__ M0cat, float* __restrict__ M1cat) {
    if (blockIdx.x == 0) {
        __shared__ int tmp[1024];
        int t = threadIdx.x;
        int base = t * 20;
        int v[20]; int s = 0;
#pragma unroll
        for (int i = 0; i < 20; ++i) {
            int idx = base + i;
            int c = (idx < NN) ? cnt[idx] : 0;
            v[i] = s; s += c;
        }
        tmp[t] = s;
        __syncthreads();
        for (int off = 1; off < 1024; off <<= 1) {
            int x = (t >= off) ? tmp[t - off] : 0;
            __syncthreads();
            tmp[t] += x;
            __syncthreads();
        }
        int tb = (t > 0) ? tmp[t - 1] : 0;
#pragma unroll
        for (int i = 0; i < 20; ++i) {
            int idx = base + i;
            if (idx < NN) { int r = tb + v[i]; rowptr[idx] = r; wptr[idx] = r; }
        }
        if (t == 1023) rowptr[NN] = NE;
    } else {
        int i = (blockIdx.x - 1) * 1024 + threadIdx.x;   // grid 9 -> 0..8191
        if (i < 1536) {
            int cp = i / 48, c = i % 48;
            float a = 0.f;
            if (c < 32) { for (int j = 0; j < C0O; ++j) a += wq0[cp*C0O+j] * wk00[c*C0O+j]; }
            else        { for (int j = 0; j < C0O; ++j) a += wq0[cp*C0O+j] * wk10[(c-32)*C0O+j]; }
            wqkc[i] = a;
        } else if (i < 1536 + 5120) {
            int k = i - 1536;
            int r = k >> 6, j = k & 63;
            M0cat[k] = (r < 32) ? wv00[r*64+j] : (r < 48) ? wv10[(r-32)*64+j] : ws0[(r-48)*64+j];
        } else if (i < 1536 + 5120 + 1024) {
            int k = i - 6656;
            int r = k >> 4, f = k & 15;
            M1cat[k] = (r < 16) ? wv11[r*16+f] : (r < 48) ? wv01[(r-16)*16+f] : ws1[(r-48)*16+f];
        }
    }
}

// ---- kC: scatter src node ids into dst-sorted CSR order ----
__global__ __launch_bounds__(256) void se3_scatter(
    const int* __restrict__ ei, int* __restrict__ wptr, int* __restrict__ csr_src) {
    int e = blockIdx.x * 256 + threadIdx.x;
    if (e >= NE) return;
    int d = ei[NE + e];
    int off = atomicAdd(&wptr[d], 1);
    csr_src[off] = ei[e];
}

// ---- kF: DUAL-node per wave (ILP x2 on the latency-bound chain). 1 wave/block,
//      grid NN/2. Both nodes' gathers issue before ONE fence; logits/softmax
//      chains interleave; epilogue shares M0cat/M1cat row loads. Round-10
//      proven per-node math, duplicated A/B. No launch_bounds VGPR cap
//      (round 8: cap -> spill). ----
__global__ void se3_fused(
    const float* __restrict__ x0, const float* __restrict__ x1,
    const float* __restrict__ pos, const float* __restrict__ wqkc,
    const int* __restrict__ rowptr, const int* __restrict__ csr_src,
    const float* __restrict__ M0cat, const float* __restrict__ M1cat,
    const int* __restrict__ flag, void* __restrict__ out) {
    __shared__ __align__(16) float rows[2][16][RSTR];
    __shared__ float sq[2][48];

    int lane = threadIdx.x;
    int nA = blockIdx.x * 2, nB = nA + 1;
    float (*RA)[RSTR] = rows[0];
    float (*RB)[RSTR] = rows[1];

    // ---- inline qvec for both nodes (shared wqkc load) ----
    float x0A = (lane < 32) ? x0[(size_t)nA * 32 + lane] : 0.f;
    float x0B = (lane < 32) ? x0[(size_t)nB * 32 + lane] : 0.f;
    {
        int li = (lane < 48) ? lane : 0;
        float qhA = 0.f, qhB = 0.f;
        for (int cp = 0; cp < 32; ++cp) {
            float wv = wqkc[cp * 48 + li];
            qhA += __shfl(x0A, cp) * wv;
            qhB += __shfl(x0B, cp) * wv;
        }
        if (lane < 48) { sq[0][lane] = qhA; sq[1][lane] = qhB; }
    }
    float pxA = pos[nA*3], pyA = pos[nA*3+1], pzA = pos[nA*3+2];
    float pxB = pos[nB*3], pyB = pos[nB*3+1], pzB = pos[nB*3+2];
    int p0A = rowptr[nA], degA = rowptr[nA+1] - p0A;
    int p0B = rowptr[nB], degB = rowptr[nB+1] - p0B;
    int degM = max(degA, degB);

    float mA = -INFINITY, zzA = 0.f, aA = 0.f, bA = 0.f, CxA = 0.f, CyA = 0.f, CzA = 0.f;
    float mB = -INFINITY, zzB = 0.f, aB = 0.f, bB = 0.f, CxB = 0.f, CyB = 0.f, CzB = 0.f;
    int e4 = lane >> 2, j4 = lane & 3;
    int cc = (lane >= 32 && lane < 48) ? (lane - 32) : 0;

    for (int base = 0; base < degM; base += 16) {
        int nchA = min(16, max(degA - base, 0));
        int nchB = min(16, max(degB - base, 0));
        float YxA = 0.f, YyA = 0.f, YzA = 0.f;
        float YxB = 0.f, YyB = 0.f, YzB = 0.f;
        // ---- stage BOTH nodes (latencies overlap), then one fence ----
        if (e4 < nchA) {
            int s_e = csr_src[p0A + base + e4];
            float rx = pxA - pos[s_e*3], ry = pyA - pos[s_e*3+1], rz = pzA - pos[s_e*3+2];
            float inv = 1.f / (sqrtf(rx*rx + ry*ry + rz*rz) + EPSF);
            YxA = rx*inv; YyA = ry*inv; YzA = rz*inv;
            const float4* px0 = (const float4*)(x0 + (size_t)s_e * 32);
            *(float4*)&RA[e4][j4*8]   = px0[j4*2];
            *(float4*)&RA[e4][j4*8+4] = px0[j4*2+1];
            const float4* px1 = (const float4*)(x1 + (size_t)s_e * 48);
            *(float4*)&RA[e4][32+j4*12]   = px1[j4*3];
            *(float4*)&RA[e4][32+j4*12+4] = px1[j4*3+1];
            *(float4*)&RA[e4][32+j4*12+8] = px1[j4*3+2];
        }
        if (e4 < nchB) {
            int s_e = csr_src[p0B + base + e4];
            float rx = pxB - pos[s_e*3], ry = pyB - pos[s_e*3+1], rz = pzB - pos[s_e*3+2];
            float inv = 1.f / (sqrtf(rx*rx + ry*ry + rz*rz) + EPSF);
            YxB = rx*inv; YyB = ry*inv; YzB = rz*inv;
            const float4* px0 = (const float4*)(x0 + (size_t)s_e * 32);
            *(float4*)&RB[e4][j4*8]   = px0[j4*2];
            *(float4*)&RB[e4][j4*8+4] = px0[j4*2+1];
            const float4* px1 = (const float4*)(x1 + (size_t)s_e * 48);
            *(float4*)&RB[e4][32+j4*12]   = px1[j4*3];
            *(float4*)&RB[e4][32+j4*12+4] = px1[j4*3+1];
            *(float4*)&RB[e4][32+j4*12+8] = px1[j4*3+2];
        }
        lds_fence();   // stage + sq writes visible before cross-lane reads
        // ---- logits both: lane (e4,j4) covers features c = j4+4k ----
        float pA = 0.f, pB = 0.f;
        if (e4 < nchA) {
#pragma unroll
            for (int k = 0; k < 12; ++k) {
                int c = j4 + 4*k;
                float kv;
                if (c < 32) kv = RA[e4][c];
                else {
                    int c1 = c - 32;
                    kv = RA[e4][32+3*c1]*YxA + RA[e4][32+3*c1+1]*YyA + RA[e4][32+3*c1+2]*YzA;
                }
                pA += kv * sq[0][c];
            }
        }
        if (e4 < nchB) {
#pragma unroll
            for (int k = 0; k < 12; ++k) {
                int c = j4 + 4*k;
                float kv;
                if (c < 32) kv = RB[e4][c];
                else {
                    int c1 = c - 32;
                    kv = RB[e4][32+3*c1]*YxB + RB[e4][32+3*c1+1]*YyB + RB[e4][32+3*c1+2]*YzB;
                }
                pB += kv * sq[1][c];
            }
        }
        pA += __shfl_xor(pA, 1);  pB += __shfl_xor(pB, 1);
        pA += __shfl_xor(pA, 2);  pB += __shfl_xor(pB, 2);
        float lgA = (e4 < nchA) ? pA * 0.125f : -INFINITY;
        float lgB = (e4 < nchB) ? pB * 0.125f : -INFINITY;
        float mcA = lgA, mcB = lgB;
        mcA = fmaxf(mcA, __shfl_xor(mcA, 4));  mcB = fmaxf(mcB, __shfl_xor(mcB, 4));
        mcA = fmaxf(mcA, __shfl_xor(mcA, 8));  mcB = fmaxf(mcB, __shfl_xor(mcB, 8));
        mcA = fmaxf(mcA, __shfl_xor(mcA, 16)); mcB = fmaxf(mcB, __shfl_xor(mcB, 16));
        mcA = fmaxf(mcA, __shfl_xor(mcA, 32)); mcB = fmaxf(mcB, __shfl_xor(mcB, 32));
        float nmA = fmaxf(mA, mcA), nmB = fmaxf(mB, mcB);
        float f0A = __expf(mA - nmA), f0B = __expf(mB - nmB);
        float wA = (e4 < nchA) ? __expf(lgA - nmA) : 0.f;
        float wB = (e4 < nchB) ? __expf(lgB - nmB) : 0.f;
        float sA = (j4 == 0) ? wA : 0.f;
        float sB = (j4 == 0) ? wB : 0.f;
        sA += __shfl_xor(sA, 1);  sB += __shfl_xor(sB, 1);
        sA += __shfl_xor(sA, 2);  sB += __shfl_xor(sB, 2);
        sA += __shfl_xor(sA, 4);  sB += __shfl_xor(sB, 4);
        sA += __shfl_xor(sA, 8);  sB += __shfl_xor(sB, 8);
        sA += __shfl_xor(sA, 16); sB += __shfl_xor(sB, 16);
        sA += __shfl_xor(sA, 32); sB += __shfl_xor(sB, 32);
        zzA = zzA * f0A + sA;  mA = nmA;
        zzB = zzB * f0B + sB;  mB = nmB;
        aA *= f0A; bA *= f0A; CxA *= f0A; CyA *= f0A; CzA *= f0A;
        aB *= f0B; bB *= f0B; CxB *= f0B; CyB *= f0B; CzB *= f0B;
        // ---- Phase B both; w/Y broadcast from lane 4e ----
#pragma unroll 4
        for (int e = 0; e < nchA; ++e) {
            float we = __shfl(wA, e * 4);
            float Y0 = __shfl(YxA, e * 4);
            float Y1 = __shfl(YyA, e * 4);
            float Y2 = __shfl(YzA, e * 4);
            float x1v = (lane < 48) ? RA[e][32 + lane] : 0.f;
            if (lane < 32) {
                float wx = we * RA[e][lane];
                aA += wx; CxA += wx * Y0; CyA += wx * Y1; CzA += wx * Y2;
            } else if (lane < 48) {
                float xd = RA[e][32+3*cc]*Y0 + RA[e][32+3*cc+1]*Y1 + RA[e][32+3*cc+2]*Y2;
                aA += we * xd;
            }
            bA += we * x1v;
        }
#pragma unroll 4
        for (int e = 0; e < nchB; ++e) {
            float we = __shfl(wB, e * 4);
            float Y0 = __shfl(YxB, e * 4);
            float Y1 = __shfl(YyB, e * 4);
            float Y2 = __shfl(YzB, e * 4);
            float x1v = (lane < 48) ? RB[e][32 + lane] : 0.f;
            if (lane < 32) {
                float wx = we * RB[e][lane];
                aB += wx; CxB += wx * Y0; CyB += wx * Y1; CzB += wx * Y2;
            } else if (lane < 48) {
                float xd = RB[e][32+3*cc]*Y0 + RB[e][32+3*cc+1]*Y1 + RB[e][32+3*cc+2]*Y2;
                aB += we * xd;
            }
            bB += we * x1v;
        }
        lds_fence();   // Phase-B reads done before next chunk overwrites R
    }

    // ---- epilogue both: scratch aliased onto RA/RB (dead after edge loop) ----
    float izA = 1.f / (zzA + EPSF), izB = 1.f / (zzB + EPSF);
    float* swA = (float*)rows[0];
    float* swB = (float*)rows[1];
    if (lane < 48) {
        swA[lane]       = aA * izA;                     swB[lane]       = aB * izB;
        swA[96 + lane]  = bA * izA;                     swB[96 + lane]  = bB * izB;
        swA[240 + lane] = x1[(size_t)nA * 48 + lane];   swB[240 + lane] = x1[(size_t)nB * 48 + lane];
    }
    if (lane < 32) {
        swA[48 + lane] = x0A;                           swB[48 + lane] = x0B;
        swA[144 + lane*3 + 0] = CxA * izA;              swB[144 + lane*3 + 0] = CxB * izB;
        swA[144 + lane*3 + 1] = CyA * izA;              swB[144 + lane*3 + 1] = CyB * izB;
        swA[144 + lane*3 + 2] = CzA * izA;              swB[144 + lane*3 + 2] = CzB * izB;
    }
    lds_fence();   // scratch writes visible before cross-lane reads
    int isf32 = *flag;
    float o0A = 0.f, o0B = 0.f;
    for (int r = 0; r < 80; ++r) {
        float mv = M0cat[r * 64 + lane];     // one load feeds both nodes
        o0A += swA[r] * mv;
        o0B += swB[r] * mv;
    }
    int f = lane / 3, d = lane - 3 * f;
    float o1A = 0.f, o1B = 0.f;
    if (lane < 48) {
        for (int r = 0; r < 64; ++r) {
            float mv = M1cat[r * 16 + f];
            o1A += swA[96 + 3*r + d] * mv;
            o1B += swB[96 + 3*r + d] * mv;
        }
    }

    if (isf32) {
        ((float*)out)[(size_t)nA * 64 + lane] = o0A;
        ((float*)out)[(size_t)nB * 64 + lane] = o0B;
        if (lane < 48) {
            ((float*)out)[(size_t)NN * 64 + (size_t)nA * 48 + lane] = o1A;
            ((float*)out)[(size_t)NN * 64 + (size_t)nB * 48 + lane] = o1B;
        }
    } else {
        ((bf16*)out)[(size_t)nA * 64 + lane] = __float2bfloat16(o0A);
        ((bf16*)out)[(size_t)nB * 64 + lane] = __float2bfloat16(o0B);
        if (lane < 48) {
            ((bf16*)out)[(size_t)NN * 64 + (size_t)nA * 48 + lane] = __float2bfloat16(o1A);
            ((bf16*)out)[(size_t)NN * 64 + (size_t)nB * 48 + lane] = __float2bfloat16(o1B);
        }
    }
}

extern "C" void kernel_launch(void* const* d_in, const int* in_sizes, int n_in,
                              void* d_out, int out_size, void* d_ws, size_t ws_size,
                              hipStream_t stream) {
    const int* ei = (const int*)d_in[3];

    int* flag  = (int*)d_ws;
    float* ws  = (float*)d_ws + 16;
    float* x0f  = ws;                 // 640000
    float* x1f  = x0f + 640000;       // 960000
    float* posf = x1f + 960000;       // 60000
    float* wq0    = posf + 60000;     // 2048
    float* wk00   = wq0 + 2048;       // 2048
    float* wk10   = wk00 + 2048;      // 1024
    float* wv00   = wk10 + 1024;      // 2048
    float* wv10   = wv00 + 2048;      // 1024
    float* wv01   = wv10 + 1024;      // 512
    float* wv11   = wv01 + 512;       // 256
    float* wself0 = wv11 + 256;       // 2048
    float* wself1 = wself0 + 2048;    // 256
    float* wqkc  = ws + STAGE_TOTAL;          // 1536
    float* M0cat = wqkc + 1536;               // 5120
    float* M1cat = M0cat + 5120;              // 1024
    int* cnt     = (int*)(M1cat + 1024);      // NN
    int* rowptr  = cnt + NN;                  // NN+1
    int* wptr    = rowptr + NN + 1;           // NN
    int* csr_src = wptr + NN;                 // NE   (total ~8.3 MB, proven)

    hipMemsetAsync(cnt, 0, NN * sizeof(int), stream);
    se3_convert<<<1633, 256, 0, stream>>>(d_in[0], d_in[1], d_in[2],
        d_in[4], d_in[5], d_in[6], d_in[7], d_in[8], d_in[9], d_in[10], d_in[11], d_in[12],
        ei, flag, ws, cnt);
    se3_scanw<<<9, 1024, 0, stream>>>(cnt, rowptr, wptr,
        wq0, wk00, wk10, wv00, wv10, wv01, wv11, wself0, wself1,
        wqkc, M0cat, M1cat);
    se3_scatter<<<1250, 256, 0, stream>>>(ei, wptr, csr_src);
    se3_fused<<<NN / 2, 64, 0, stream>>>(x0f, x1f, posf, wqkc, rowptr, csr_src,
        M0cat, M1cat, flag, d_out);
}

// Round 13
// 177.486 us; speedup vs baseline: 2.2396x; 1.4545x over previous
//
#include <hip/hip_runtime.h>
#include <hip/hip_bf16.h>
#include <math.h>

#define NN 20000
#define NE 320000
#define C0I 32
#define C1I 16
#define C0O 64
#define C1O 16
#define EPSF 1e-8f
#define STAGE_TOTAL 1671264   // total staged f32 elements
#define STAGE_V4    417816    // /4
#define RSTR 84               // LDS row stride (84 mod 32 = 20 -> 2-way max, free)

using bf16 = __hip_bfloat16;

__device__ __forceinline__ float bb2f(unsigned short u) {
    return __uint_as_float(((unsigned)u) << 16);
}

// wave-level LDS fence: drain outstanding ds ops + forbid compile-time motion
__device__ __forceinline__ void lds_fence() {
    asm volatile("s_waitcnt lgkmcnt(0)" ::: "memory");
    __builtin_amdgcn_sched_barrier(0);
}

// ---- kA: detect dtype + stage all float inputs as f32 + dst histogram ----
//      (cnt zeroed by hipMemsetAsync before this kernel)
__global__ __launch_bounds__(256) void se3_convert(
    const void* s0, const void* s1, const void* s2, const void* s3,
    const void* s4, const void* s5, const void* s6, const void* s7,
    const void* s8, const void* s9, const void* s10, const void* s11,
    const int* __restrict__ ei,
    int* __restrict__ flag, float* __restrict__ dst, int* __restrict__ cnt) {
    __shared__ int sj;
    if (threadIdx.x == 0) sj = 0;
    __syncthreads();
    {   // f32 data read as bf16 at even indices shows junk exponents
        const unsigned short* p = (const unsigned short*)s0;
        bool junk = false;
        int i0 = threadIdx.x * 8;
#pragma unroll
        for (int k = 0; k < 4; ++k) {
            float v = bb2f(p[i0 + k * 2]);
            if (!(fabsf(v) < 1e3f)) junk = true;
        }
        if (junk) atomicOr(&sj, 1);
    }
    __syncthreads();
    int isf32 = sj;
    int gid = blockIdx.x * 256 + threadIdx.x;
    if (gid == 0) *flag = isf32;
    if (gid < NE) atomicAdd(&cnt[ei[NE + gid]], 1);   // histogram (cnt pre-zeroed)
    if (gid >= STAGE_V4) return;

    const void* src; int off;  // vec4 units
    if      (gid < 160000) { src = s0;  off = gid; }
    else if (gid < 400000) { src = s1;  off = gid - 160000; }
    else if (gid < 415000) { src = s2;  off = gid - 400000; }
    else if (gid < 415512) { src = s3;  off = gid - 415000; }
    else if (gid < 416024) { src = s4;  off = gid - 415512; }
    else if (gid < 416280) { src = s5;  off = gid - 416024; }
    else if (gid < 416792) { src = s6;  off = gid - 416280; }
    else if (gid < 417048) { src = s7;  off = gid - 416792; }
    else if (gid < 417176) { src = s8;  off = gid - 417048; }
    else if (gid < 417240) { src = s9;  off = gid - 417176; }
    else if (gid < 417752) { src = s10; off = gid - 417240; }
    else                   { src = s11; off = gid - 417752; }

    float4 v;
    if (isf32) {
        v = ((const float4*)src)[off];
    } else {
        ushort4 u = ((const ushort4*)src)[off];
        v = make_float4(bb2f(u.x), bb2f(u.y), bb2f(u.z), bb2f(u.w));
    }
    ((float4*)dst)[gid] = v;
}

// ---- kB: block 0: exclusive scan cnt -> rowptr,wptr; blocks 1-8: weight combines ----
__global__ __launch_bounds__(1024) void se3_scanw(
    const int* __restrict__ cnt, int* __restrict__ rowptr, int* __restrict__ wptr,
    const float* __restrict__ wq0, const float* __restrict__ wk00,
    const float* __restrict__ wk10,
    const float* __restrict__ wv00, const float* __restrict__ wv10,
    const float* __restrict__ wv01, const float* __restrict__ wv11,
    const float* __restrict__ ws0, const float* __restrict__ ws1,
    float* __restrict__ wqkc, float* __restrict__ M0cat, float* __restrict__ M1cat) {
    if (blockIdx.x == 0) {
        __shared__ int tmp[1024];
        int t = threadIdx.x;
        int base = t * 20;
        int v[20]; int s = 0;
#pragma unroll
        for (int i = 0; i < 20; ++i) {
            int idx = base + i;
            int c = (idx < NN) ? cnt[idx] : 0;
            v[i] = s; s += c;
        }
        tmp[t] = s;
        __syncthreads();
        for (int off = 1; off < 1024; off <<= 1) {
            int x = (t >= off) ? tmp[t - off] : 0;
            __syncthreads();
            tmp[t] += x;
            __syncthreads();
        }
        int tb = (t > 0) ? tmp[t - 1] : 0;
#pragma unroll
        for (int i = 0; i < 20; ++i) {
            int idx = base + i;
            if (idx < NN) { int r = tb + v[i]; rowptr[idx] = r; wptr[idx] = r; }
        }
        if (t == 1023) rowptr[NN] = NE;
    } else {
        int i = (blockIdx.x - 1) * 1024 + threadIdx.x;   // grid 9 -> 0..8191
        if (i < 1536) {
            int cp = i / 48, c = i % 48;
            float a = 0.f;
            if (c < 32) { for (int j = 0; j < C0O; ++j) a += wq0[cp*C0O+j] * wk00[c*C0O+j]; }
            else        { for (int j = 0; j < C0O; ++j) a += wq0[cp*C0O+j] * wk10[(c-32)*C0O+j]; }
            wqkc[i] = a;
        } else if (i < 1536 + 5120) {
            int k = i - 1536;
            int r = k >> 6, j = k & 63;
            M0cat[k] = (r < 32) ? wv00[r*64+j] : (r < 48) ? wv10[(r-32)*64+j] : ws0[(r-48)*64+j];
        } else if (i < 1536 + 5120 + 1024) {
            int k = i - 6656;
            int r = k >> 4, f = k & 15;
            M1cat[k] = (r < 16) ? wv11[r*16+f] : (r < 48) ? wv01[(r-16)*16+f] : ws1[(r-48)*16+f];
        }
    }
}

// ---- kC: scatter src node ids into dst-sorted CSR order ----
__global__ __launch_bounds__(256) void se3_scatter(
    const int* __restrict__ ei, int* __restrict__ wptr, int* __restrict__ csr_src) {
    int e = blockIdx.x * 256 + threadIdx.x;
    if (e >= NE) return;
    int d = ei[NE + e];
    int off = atomicAdd(&wptr[d], 1);
    csr_src[off] = ei[e];
}

// ---- kF: DUAL-node per wave (ILP x2 on the latency-bound chain). 1 wave/block,
//      grid NN/2. __launch_bounds__(64) is ESSENTIAL: round 12 omitted it and
//      hipcc budgeted for 1024-thr blocks -> VGPR capped at 64 -> 320 MB spill.
//      With (64): 1 wave/WG -> full VGPR budget available. ----
__global__ __launch_bounds__(64) void se3_fused(
    const float* __restrict__ x0, const float* __restrict__ x1,
    const float* __restrict__ pos, const float* __restrict__ wqkc,
    const int* __restrict__ rowptr, const int* __restrict__ csr_src,
    const float* __restrict__ M0cat, const float* __restrict__ M1cat,
    const int* __restrict__ flag, void* __restrict__ out) {
    __shared__ __align__(16) float rows[2][16][RSTR];
    __shared__ float sq[2][48];

    int lane = threadIdx.x;
    int nA = blockIdx.x * 2, nB = nA + 1;
    float (*RA)[RSTR] = rows[0];
    float (*RB)[RSTR] = rows[1];

    // ---- inline qvec for both nodes (shared wqkc load) ----
    float x0A = (lane < 32) ? x0[(size_t)nA * 32 + lane] : 0.f;
    float x0B = (lane < 32) ? x0[(size_t)nB * 32 + lane] : 0.f;
    {
        int li = (lane < 48) ? lane : 0;
        float qhA = 0.f, qhB = 0.f;
        for (int cp = 0; cp < 32; ++cp) {
            float wv = wqkc[cp * 48 + li];
            qhA += __shfl(x0A, cp) * wv;
            qhB += __shfl(x0B, cp) * wv;
        }
        if (lane < 48) { sq[0][lane] = qhA; sq[1][lane] = qhB; }
    }
    float pxA = pos[nA*3], pyA = pos[nA*3+1], pzA = pos[nA*3+2];
    float pxB = pos[nB*3], pyB = pos[nB*3+1], pzB = pos[nB*3+2];
    int p0A = rowptr[nA], degA = rowptr[nA+1] - p0A;
    int p0B = rowptr[nB], degB = rowptr[nB+1] - p0B;
    int degM = max(degA, degB);

    float mA = -INFINITY, zzA = 0.f, aA = 0.f, bA = 0.f, CxA = 0.f, CyA = 0.f, CzA = 0.f;
    float mB = -INFINITY, zzB = 0.f, aB = 0.f, bB = 0.f, CxB = 0.f, CyB = 0.f, CzB = 0.f;
    int e4 = lane >> 2, j4 = lane & 3;
    int cc = (lane >= 32 && lane < 48) ? (lane - 32) : 0;

    for (int base = 0; base < degM; base += 16) {
        int nchA = min(16, max(degA - base, 0));
        int nchB = min(16, max(degB - base, 0));
        float YxA = 0.f, YyA = 0.f, YzA = 0.f;
        float YxB = 0.f, YyB = 0.f, YzB = 0.f;
        // ---- stage BOTH nodes (latencies overlap), then one fence ----
        if (e4 < nchA) {
            int s_e = csr_src[p0A + base + e4];
            float rx = pxA - pos[s_e*3], ry = pyA - pos[s_e*3+1], rz = pzA - pos[s_e*3+2];
            float inv = 1.f / (sqrtf(rx*rx + ry*ry + rz*rz) + EPSF);
            YxA = rx*inv; YyA = ry*inv; YzA = rz*inv;
            const float4* px0 = (const float4*)(x0 + (size_t)s_e * 32);
            *(float4*)&RA[e4][j4*8]   = px0[j4*2];
            *(float4*)&RA[e4][j4*8+4] = px0[j4*2+1];
            const float4* px1 = (const float4*)(x1 + (size_t)s_e * 48);
            *(float4*)&RA[e4][32+j4*12]   = px1[j4*3];
            *(float4*)&RA[e4][32+j4*12+4] = px1[j4*3+1];
            *(float4*)&RA[e4][32+j4*12+8] = px1[j4*3+2];
        }
        if (e4 < nchB) {
            int s_e = csr_src[p0B + base + e4];
            float rx = pxB - pos[s_e*3], ry = pyB - pos[s_e*3+1], rz = pzB - pos[s_e*3+2];
            float inv = 1.f / (sqrtf(rx*rx + ry*ry + rz*rz) + EPSF);
            YxB = rx*inv; YyB = ry*inv; YzB = rz*inv;
            const float4* px0 = (const float4*)(x0 + (size_t)s_e * 32);
            *(float4*)&RB[e4][j4*8]   = px0[j4*2];
            *(float4*)&RB[e4][j4*8+4] = px0[j4*2+1];
            const float4* px1 = (const float4*)(x1 + (size_t)s_e * 48);
            *(float4*)&RB[e4][32+j4*12]   = px1[j4*3];
            *(float4*)&RB[e4][32+j4*12+4] = px1[j4*3+1];
            *(float4*)&RB[e4][32+j4*12+8] = px1[j4*3+2];
        }
        lds_fence();   // stage + sq writes visible before cross-lane reads
        // ---- logits both: lane (e4,j4) covers features c = j4+4k ----
        float pA = 0.f, pB = 0.f;
        if (e4 < nchA) {
#pragma unroll
            for (int k = 0; k < 12; ++k) {
                int c = j4 + 4*k;
                float kv;
                if (c < 32) kv = RA[e4][c];
                else {
                    int c1 = c - 32;
                    kv = RA[e4][32+3*c1]*YxA + RA[e4][32+3*c1+1]*YyA + RA[e4][32+3*c1+2]*YzA;
                }
                pA += kv * sq[0][c];
            }
        }
        if (e4 < nchB) {
#pragma unroll
            for (int k = 0; k < 12; ++k) {
                int c = j4 + 4*k;
                float kv;
                if (c < 32) kv = RB[e4][c];
                else {
                    int c1 = c - 32;
                    kv = RB[e4][32+3*c1]*YxB + RB[e4][32+3*c1+1]*YyB + RB[e4][32+3*c1+2]*YzB;
                }
                pB += kv * sq[1][c];
            }
        }
        pA += __shfl_xor(pA, 1);  pB += __shfl_xor(pB, 1);
        pA += __shfl_xor(pA, 2);  pB += __shfl_xor(pB, 2);
        float lgA = (e4 < nchA) ? pA * 0.125f : -INFINITY;
        float lgB = (e4 < nchB) ? pB * 0.125f : -INFINITY;
        float mcA = lgA, mcB = lgB;
        mcA = fmaxf(mcA, __shfl_xor(mcA, 4));  mcB = fmaxf(mcB, __shfl_xor(mcB, 4));
        mcA = fmaxf(mcA, __shfl_xor(mcA, 8));  mcB = fmaxf(mcB, __shfl_xor(mcB, 8));
        mcA = fmaxf(mcA, __shfl_xor(mcA, 16)); mcB = fmaxf(mcB, __shfl_xor(mcB, 16));
        mcA = fmaxf(mcA, __shfl_xor(mcA, 32)); mcB = fmaxf(mcB, __shfl_xor(mcB, 32));
        float nmA = fmaxf(mA, mcA), nmB = fmaxf(mB, mcB);
        float f0A = __expf(mA - nmA), f0B = __expf(mB - nmB);
        float wA = (e4 < nchA) ? __expf(lgA - nmA) : 0.f;
        float wB = (e4 < nchB) ? __expf(lgB - nmB) : 0.f;
        float sA = (j4 == 0) ? wA : 0.f;
        float sB = (j4 == 0) ? wB : 0.f;
        sA += __shfl_xor(sA, 1);  sB += __shfl_xor(sB, 1);
        sA += __shfl_xor(sA, 2);  sB += __shfl_xor(sB, 2);
        sA += __shfl_xor(sA, 4);  sB += __shfl_xor(sB, 4);
        sA += __shfl_xor(sA, 8);  sB += __shfl_xor(sB, 8);
        sA += __shfl_xor(sA, 16); sB += __shfl_xor(sB, 16);
        sA += __shfl_xor(sA, 32); sB += __shfl_xor(sB, 32);
        zzA = zzA * f0A + sA;  mA = nmA;
        zzB = zzB * f0B + sB;  mB = nmB;
        aA *= f0A; bA *= f0A; CxA *= f0A; CyA *= f0A; CzA *= f0A;
        aB *= f0B; bB *= f0B; CxB *= f0B; CyB *= f0B; CzB *= f0B;
        // ---- Phase B both; w/Y broadcast from lane 4e ----
#pragma unroll 4
        for (int e = 0; e < nchA; ++e) {
            float we = __shfl(wA, e * 4);
            float Y0 = __shfl(YxA, e * 4);
            float Y1 = __shfl(YyA, e * 4);
            float Y2 = __shfl(YzA, e * 4);
            float x1v = (lane < 48) ? RA[e][32 + lane] : 0.f;
            if (lane < 32) {
                float wx = we * RA[e][lane];
                aA += wx; CxA += wx * Y0; CyA += wx * Y1; CzA += wx * Y2;
            } else if (lane < 48) {
                float xd = RA[e][32+3*cc]*Y0 + RA[e][32+3*cc+1]*Y1 + RA[e][32+3*cc+2]*Y2;
                aA += we * xd;
            }
            bA += we * x1v;
        }
#pragma unroll 4
        for (int e = 0; e < nchB; ++e) {
            float we = __shfl(wB, e * 4);
            float Y0 = __shfl(YxB, e * 4);
            float Y1 = __shfl(YyB, e * 4);
            float Y2 = __shfl(YzB, e * 4);
            float x1v = (lane < 48) ? RB[e][32 + lane] : 0.f;
            if (lane < 32) {
                float wx = we * RB[e][lane];
                aB += wx; CxB += wx * Y0; CyB += wx * Y1; CzB += wx * Y2;
            } else if (lane < 48) {
                float xd = RB[e][32+3*cc]*Y0 + RB[e][32+3*cc+1]*Y1 + RB[e][32+3*cc+2]*Y2;
                aB += we * xd;
            }
            bB += we * x1v;
        }
        lds_fence();   // Phase-B reads done before next chunk overwrites R
    }

    // ---- epilogue both: scratch aliased onto RA/RB (dead after edge loop) ----
    float izA = 1.f / (zzA + EPSF), izB = 1.f / (zzB + EPSF);
    float* swA = (float*)rows[0];
    float* swB = (float*)rows[1];
    if (lane < 48) {
        swA[lane]       = aA * izA;                     swB[lane]       = aB * izB;
        swA[96 + lane]  = bA * izA;                     swB[96 + lane]  = bB * izB;
        swA[240 + lane] = x1[(size_t)nA * 48 + lane];   swB[240 + lane] = x1[(size_t)nB * 48 + lane];
    }
    if (lane < 32) {
        swA[48 + lane] = x0A;                           swB[48 + lane] = x0B;
        swA[144 + lane*3 + 0] = CxA * izA;              swB[144 + lane*3 + 0] = CxB * izB;
        swA[144 + lane*3 + 1] = CyA * izA;              swB[144 + lane*3 + 1] = CyB * izB;
        swA[144 + lane*3 + 2] = CzA * izA;              swB[144 + lane*3 + 2] = CzB * izB;
    }
    lds_fence();   // scratch writes visible before cross-lane reads
    int isf32 = *flag;
    float o0A = 0.f, o0B = 0.f;
    for (int r = 0; r < 80; ++r) {
        float mv = M0cat[r * 64 + lane];     // one load feeds both nodes
        o0A += swA[r] * mv;
        o0B += swB[r] * mv;
    }
    int f = lane / 3, d = lane - 3 * f;
    float o1A = 0.f, o1B = 0.f;
    if (lane < 48) {
        for (int r = 0; r < 64; ++r) {
            float mv = M1cat[r * 16 + f];
            o1A += swA[96 + 3*r + d] * mv;
            o1B += swB[96 + 3*r + d] * mv;
        }
    }

    if (isf32) {
        ((float*)out)[(size_t)nA * 64 + lane] = o0A;
        ((float*)out)[(size_t)nB * 64 + lane] = o0B;
        if (lane < 48) {
            ((float*)out)[(size_t)NN * 64 + (size_t)nA * 48 + lane] = o1A;
            ((float*)out)[(size_t)NN * 64 + (size_t)nB * 48 + lane] = o1B;
        }
    } else {
        ((bf16*)out)[(size_t)nA * 64 + lane] = __float2bfloat16(o0A);
        ((bf16*)out)[(size_t)nB * 64 + lane] = __float2bfloat16(o0B);
        if (lane < 48) {
            ((bf16*)out)[(size_t)NN * 64 + (size_t)nA * 48 + lane] = __float2bfloat16(o1A);
            ((bf16*)out)[(size_t)NN * 64 + (size_t)nB * 48 + lane] = __float2bfloat16(o1B);
        }
    }
}

extern "C" void kernel_launch(void* const* d_in, const int* in_sizes, int n_in,
                              void* d_out, int out_size, void* d_ws, size_t ws_size,
                              hipStream_t stream) {
    const int* ei = (const int*)d_in[3];

    int* flag  = (int*)d_ws;
    float* ws  = (float*)d_ws + 16;
    float* x0f  = ws;                 // 640000
    float* x1f  = x0f + 640000;       // 960000
    float* posf = x1f + 960000;       // 60000
    float* wq0    = posf + 60000;     // 2048
    float* wk00   = wq0 + 2048;       // 2048
    float* wk10   = wk00 + 2048;      // 1024
    float* wv00   = wk10 + 1024;      // 2048
    float* wv10   = wv00 + 2048;      // 1024
    float* wv01   = wv10 + 1024;      // 512
    float* wv11   = wv01 + 512;       // 256
    float* wself0 = wv11 + 256;       // 2048
    float* wself1 = wself0 + 2048;    // 256
    float* wqkc  = ws + STAGE_TOTAL;          // 1536
    float* M0cat = wqkc + 1536;               // 5120
    float* M1cat = M0cat + 5120;              // 1024
    int* cnt     = (int*)(M1cat + 1024);      // NN
    int* rowptr  = cnt + NN;                  // NN+1
    int* wptr    = rowptr + NN + 1;           // NN
    int* csr_src = wptr + NN;                 // NE   (total ~8.3 MB, proven)

    hipMemsetAsync(cnt, 0, NN * sizeof(int), stream);
    se3_convert<<<1633, 256, 0, stream>>>(d_in[0], d_in[1], d_in[2],
        d_in[4], d_in[5], d_in[6], d_in[7], d_in[8], d_in[9], d_in[10], d_in[11], d_in[12],
        ei, flag, ws, cnt);
    se3_scanw<<<9, 1024, 0, stream>>>(cnt, rowptr, wptr,
        wq0, wk00, wk10, wv00, wv10, wv01, wv11, wself0, wself1,
        wqkc, M0cat, M1cat);
    se3_scatter<<<1250, 256, 0, stream>>>(ei, wptr, csr_src);
    se3_fused<<<NN / 2, 64, 0, stream>>>(x0f, x1f, posf, wqkc, rowptr, csr_src,
        M0cat, M1cat, flag, d_out);
}